// Round 5
// baseline (268.940 us; speedup 1.0000x reference)
//
#include <hip/hip_runtime.h>
#include <stdint.h>

// ConstraintLoss fused reduction, streaming + LDS-redistribute version.
// predictions/targets: (B,240) f32; inputs: (B,13) f32; out: scalar f32.
//
// Phase 1: block's pred slab (64 rows x 960B) streamed global->LDS via
//          global_load_lds (width 16, fully contiguous = the 6.3 TB/s
//          pattern); targ streamed into registers; MSE computed from
//          (own LDS slots, targ regs) pre-barrier.
// Phase 2: row-structured dynamics/obstacle math from LDS (4 threads/row),
//          telescoped dynamics => pure elementwise sums.

#define NTHREADS 256
#define ROWS_PER_BLOCK 64
#define F4_PER_BLOCK (ROWS_PER_BLOCK * 60)       // 3840 float4
#define F4_PER_THREAD (F4_PER_BLOCK / NTHREADS)  // 15

__global__ __launch_bounds__(NTHREADS, 2) void constraint_main_kernel(
    const float* __restrict__ pred,
    const float* __restrict__ targ,
    const float* __restrict__ inp,
    float* __restrict__ partial,   // 2 floats per block, overwritten
    int B)
{
    const float DT = 0.25f;
    const int tid = threadIdx.x;

    __shared__ float4 spred[F4_PER_BLOCK];          // 61440 B
    __shared__ float  sinp[ROWS_PER_BLOCK * 13];    // 3328 B

    const size_t nf4     = (size_t)B * 60;
    const size_t blk_f4  = (size_t)blockIdx.x * F4_PER_BLOCK;
    const float4* pred4  = reinterpret_cast<const float4*>(pred);
    const float4* targ4  = reinterpret_cast<const float4*>(targ);

    // ---- Phase 1a: async global->LDS for pred (contiguous streaming) ----
    #pragma unroll
    for (int i = 0; i < F4_PER_THREAD; ++i) {
        const int f = i * NTHREADS + tid;
        size_t g = blk_f4 + (size_t)f;
        if (g >= nf4) g = nf4 - 1;                 // clamp (B%64==0 in practice)
        __builtin_amdgcn_global_load_lds(
            (const __attribute__((address_space(1))) void*)(pred4 + g),
            (__attribute__((address_space(3))) void*)(&spred[f]),
            16, 0, 0);
    }

    // ---- Phase 1b: targ into registers (contiguous streaming) ----
    float4 t[F4_PER_THREAD];
    #pragma unroll
    for (int i = 0; i < F4_PER_THREAD; ++i) {
        const int f = i * NTHREADS + tid;
        size_t g = blk_f4 + (size_t)f;
        if (g >= nf4) g = nf4 - 1;
        t[i] = targ4[g];
    }

    // ---- Phase 1c: stage this block's inputs (64 x 13 f32) into LDS ----
    {
        const size_t base = (size_t)blockIdx.x * (ROWS_PER_BLOCK * 13);
        const size_t lim  = (size_t)B * 13;
        for (int idx = tid; idx < ROWS_PER_BLOCK * 13; idx += NTHREADS) {
            float v = 0.0f;
            if (base + idx < lim) v = inp[base + idx];
            sinp[idx] = v;
        }
    }

    // Drain all async LDS writes + global loads before touching spred.
    asm volatile("s_waitcnt vmcnt(0)" ::: "memory");
    __builtin_amdgcn_sched_barrier(0);

    // ---- MSE from own LDS slots (written by this wave) + targ regs ----
    float mse = 0.0f;
    #pragma unroll
    for (int i = 0; i < F4_PER_THREAD; ++i) {
        const int f = i * NTHREADS + tid;
        const float4 pv = spred[f];
        const float4 tv = t[i];
        float d0 = pv.x - tv.x, d1 = pv.y - tv.y;
        float d2 = pv.z - tv.z, d3 = pv.w - tv.w;
        mse += d0 * d0 + d1 * d1 + d2 * d2 + d3 * d3;
    }

    __syncthreads();   // spred/sinp now visible block-wide

    // ---- Phase 2: row-structured math from LDS, 4 threads per row ----
    float cons = 0.0f;
    {
        const int sub  = tid & 3;
        const int rloc = tid >> 2;
        const int row  = blockIdx.x * ROWS_PER_BLOCK + rloc;

        if (row < B) {
            const float*  in   = &sinp[rloc * 13];
            const float4* prow = &spred[rloc * 60];

            const float ox0 = in[4],  oy0 = in[5];
            const float ox1 = in[7],  oy1 = in[8];
            const float ox2 = in[10], oy2 = in[11];

            float cv = 0.0f, sv = 0.0f, sum_dist = 0.0f;
            float sum_a = 0.0f, sum_w = 0.0f;
            float xlx = 0.0f, xly = 0.0f, xlth = 0.0f, xlv = 0.0f;  // x[39] (sub 3)

            // States x[k], k = sub + 4*i (float4 = px,py,th,v)
            #pragma unroll
            for (int i = 0; i < 10; ++i) {
                const int k = sub + 4 * i;
                const float4 pv = prow[k];
                if (k != 39) {                 // states 0..38 feed telescoped sums
                    float s, c;
                    __sincosf(pv.z, &s, &c);
                    cv += pv.w * c;
                    sv += pv.w * s;
                } else {
                    xlx = pv.x; xly = pv.y; xlth = pv.z; xlv = pv.w;
                }
                float dx, dy;
                dx = pv.x - ox0; dy = pv.y - oy0; sum_dist += sqrtf(dx * dx + dy * dy);
                dx = pv.x - ox1; dy = pv.y - oy1; sum_dist += sqrtf(dx * dx + dy * dy);
                dx = pv.x - ox2; dy = pv.y - oy2; sum_dist += sqrtf(dx * dx + dy * dy);
            }

            // Controls: float4 = (a,w,a,w)
            #pragma unroll
            for (int i = 0; i < 5; ++i) {
                const float4 pv = prow[40 + sub + 4 * i];
                sum_a += pv.x + pv.z;
                sum_w += pv.y + pv.w;
            }

            // Combine partials across the 4 lanes of this row's group.
            #pragma unroll
            for (int m = 1; m < 4; m <<= 1) {
                cv       += __shfl_xor(cv, m);
                sv       += __shfl_xor(sv, m);
                sum_a    += __shfl_xor(sum_a, m);
                sum_w    += __shfl_xor(sum_w, m);
                sum_dist += __shfl_xor(sum_dist, m);
            }

            // Bring x[39] (held by sub 3) to the whole 4-lane group.
            const int lane = tid & 63;
            const int src  = lane | 3;
            xlx  = __shfl(xlx,  src);
            xly  = __shfl(xly,  src);
            xlth = __shfl(xlth, src);
            xlv  = __shfl(xlv,  src);

            if (sub == 0) {
                const float x0px = in[0], x0py = in[1], x0th = in[2], x0v = in[3];
                const float r0 = in[6]  + 2.0f;
                const float r1 = in[9]  + 2.0f;
                const float r2 = in[12] + 2.0f;
                float s, c;
                __sincosf(x0th, &s, &c);
                cv += x0v * c;       // prev for k=0 is x0
                sv += x0v * s;

                float rr0 = xlx  - x0px - DT * cv;
                float rr1 = xly  - x0py - DT * sv;
                float rr2 = xlth - x0th - DT * sum_w;
                float rr3 = xlv  - x0v  - DT * sum_a;
                float dyn_err = sqrtf(rr0 * rr0 + rr1 * rr1 + rr2 * rr2 + rr3 * rr3);
                float rad2sum = r0 * r0 + r1 * r1 + r2 * r2;
                cons = dyn_err + sum_dist - 40.0f * rad2sum;
            }
        }
    }

    // ---- Wave-level reduction (64 lanes), then cross-wave via LDS ----
    #pragma unroll
    for (int off = 32; off > 0; off >>= 1) {
        mse  += __shfl_down(mse,  off);
        cons += __shfl_down(cons, off);
    }

    __shared__ float smse[NTHREADS / 64];
    __shared__ float scons[NTHREADS / 64];
    const int wid  = threadIdx.x >> 6;
    const int lane = threadIdx.x & 63;
    if (lane == 0) { smse[wid] = mse; scons[wid] = cons; }
    __syncthreads();
    if (threadIdx.x == 0) {
        float m = smse[0] + smse[1] + smse[2] + smse[3];
        float c = scons[0] + scons[1] + scons[2] + scons[3];
        partial[2 * blockIdx.x]     = m;
        partial[2 * blockIdx.x + 1] = c;
    }
}

__global__ __launch_bounds__(256) void finalize_kernel(
    const float* __restrict__ partial, float* __restrict__ out,
    int nblocks, int B)
{
    float m = 0.0f, c = 0.0f;
    for (int i = threadIdx.x; i < nblocks; i += 256) {
        m += partial[2 * i];
        c += partial[2 * i + 1];
    }
    #pragma unroll
    for (int off = 32; off > 0; off >>= 1) {
        m += __shfl_down(m, off);
        c += __shfl_down(c, off);
    }
    __shared__ float sm[4], sc[4];
    const int wid  = threadIdx.x >> 6;
    const int lane = threadIdx.x & 63;
    if (lane == 0) { sm[wid] = m; sc[wid] = c; }
    __syncthreads();
    if (threadIdx.x == 0) {
        float mm = sm[0] + sm[1] + sm[2] + sm[3];
        float cc = sc[0] + sc[1] + sc[2] + sc[3];
        float nb = (float)B;
        out[0] = mm / (nb * 240.0f) + cc / nb;
    }
}

extern "C" void kernel_launch(void* const* d_in, const int* in_sizes, int n_in,
                              void* d_out, int out_size, void* d_ws, size_t ws_size,
                              hipStream_t stream) {
    const float* pred = (const float*)d_in[0];
    const float* targ = (const float*)d_in[1];
    const float* inp  = (const float*)d_in[2];
    float* out = (float*)d_out;
    float* ws  = (float*)d_ws;

    const int B = in_sizes[0] / 240;
    const int grid = (B + ROWS_PER_BLOCK - 1) / ROWS_PER_BLOCK;

    constraint_main_kernel<<<grid, NTHREADS, 0, stream>>>(pred, targ, inp, ws, B);
    finalize_kernel<<<1, 256, 0, stream>>>(ws, out, grid, B);
}